// Round 3
// baseline (492.517 us; speedup 1.0000x reference)
//
#include <hip/hip_runtime.h>
#include <hip/hip_bf16.h>

#define D 128
#define SCAN_C 512
#define BKT 512        // nodes per bucket
#define BKT_SHIFT 9
#define CH 256         // edge chunks
#define NBMAX 512
#define MREP 64        // min-buffer replicas

typedef __attribute__((ext_vector_type(8))) short bf16x8;
typedef __attribute__((ext_vector_type(4))) float f32x4;

// ---------------- bf16 helpers (manual, RN-even) ----------------
__device__ __forceinline__ float bf16_to_f(unsigned int u) {
    union { unsigned int i; float f; } c; c.i = u << 16; return c.f;
}
__device__ __forceinline__ unsigned short f_to_bf16(float f) {
    union { float f; unsigned int i; } c; c.f = f;
    unsigned int r = c.i + 0x7FFFu + ((c.i >> 16) & 1u);
    return (unsigned short)(r >> 16);
}

// ---------------- runtime dtype detection ----------------
__global__ void detect_kernel(const unsigned short* __restrict__ xr,
                              const int* __restrict__ er, int* __restrict__ flag) {
    int plaus = 0;
    for (int i = 0; i < 64; ++i) {
        unsigned short u = xr[2 * i];
        int e = (u >> 7) & 0xFF;
        if (e >= 0x74 && e <= 0x82) plaus++;
    }
    flag[1] = (plaus >= 32) ? 1 : 0;
    int zeros = 0;
    for (int i = 1; i < 128; i += 2) zeros += (er[i] == 0);
    flag[0] = (zeros >= 60) ? 1 : 0;
}

__device__ __forceinline__ int load_idx(const void* p, long long i, int is64) {
    if (is64) return (int)((const long long*)p)[i];
    return ((const int*)p)[i];
}

// ---------------- conversions ----------------
__global__ void cvt_x_kernel(const void* __restrict__ src, const int* __restrict__ flag,
                             unsigned short* __restrict__ dst, int n) {
    if (flag[1]) return;   // bf16 input: no copy needed
    int i = blockIdx.x * blockDim.x + threadIdx.x;
    int stride = gridDim.x * blockDim.x;
    const float* s = (const float*)src;
    for (; i < n; i += stride) dst[i] = f_to_bf16(s[i]);
}

__global__ void cvt_f_kernel(const void* __restrict__ src, const int* __restrict__ flag,
                             float* __restrict__ dst, int n) {
    int is_bf16 = flag[1];
    int i = blockIdx.x * blockDim.x + threadIdx.x;
    int stride = gridDim.x * blockDim.x;
    if (is_bf16) {
        const unsigned short* s = (const unsigned short*)src;
        for (; i < n; i += stride) dst[i] = bf16_to_f(s[i]);
    } else {
        const float* s = (const float*)src;
        for (; i < n; i += stride) dst[i] = s[i];
    }
}

// ---------------- pack W into MFMA B-fragment order ----------------
__global__ void packW_kernel(const void* __restrict__ Wl0, const void* __restrict__ Wr0,
                             const int* __restrict__ flag, unsigned short* __restrict__ Wpack,
                             int L) {
    int idx = blockIdx.x * blockDim.x + threadIdx.x;
    if (idx >= L * 8 * 8 * 64) return;
    int lane = idx & 63;
    int ks = (idx >> 6) & 7;
    int nt = (idx >> 9) & 7;
    int layer = idx >> 12;
    int n = nt * 16 + (lane & 15);
    int k0 = ks * 32 + (lane >> 4) * 8;
    int is_bf16 = flag[1];
    unsigned short outv[8];
#pragma unroll
    for (int j = 0; j < 8; ++j) {
        int k = k0 + j;
        size_t off = (size_t)layer * D * D + (size_t)n * D + (k & 127);
        float v;
        if (is_bf16) {
            const unsigned short* W = (const unsigned short*)((k < D) ? Wl0 : Wr0);
            v = bf16_to_f(W[off]);
        } else {
            const float* W = (const float*)((k < D) ? Wl0 : Wr0);
            v = W[off];
        }
        outv[j] = f_to_bf16(v);
    }
    *(uint4*)&Wpack[(size_t)idx * 8] = *(uint4*)outv;
}

// ---------------- bucketed CSR build ----------------
__global__ void bucket_hist_kernel(const void* __restrict__ eidx, const int* __restrict__ flag,
                                   int* __restrict__ counts2D, int E, int NB, int EPC) {
    __shared__ int hist[NBMAX];
    int c = blockIdx.x;
    for (int i = threadIdx.x; i < NB; i += blockDim.x) hist[i] = 0;
    __syncthreads();
    int is64 = flag[0];
    int end = min(E, (c + 1) * EPC);
    for (int e = c * EPC + threadIdx.x; e < end; e += blockDim.x) {
        int d = load_idx(eidx, (long long)E + e, is64);
        atomicAdd(&hist[d >> BKT_SHIFT], 1);
    }
    __syncthreads();
    for (int i = threadIdx.x; i < NB; i += blockDim.x)
        counts2D[i * CH + c] = hist[i];
}

__global__ void gscan1_kernel(const int* __restrict__ in, int* __restrict__ blockSums, int n) {
    __shared__ int red[256];
    int base = blockIdx.x * SCAN_C;
    int t = threadIdx.x;
    int s = 0;
    if (base + t < n) s += in[base + t];
    if (base + t + 256 < n) s += in[base + t + 256];
    red[t] = s;
    __syncthreads();
    for (int off = 128; off > 0; off >>= 1) {
        if (t < off) red[t] += red[t + off];
        __syncthreads();
    }
    if (t == 0) blockSums[blockIdx.x] = red[0];
}

__global__ void gscan2_kernel(int* __restrict__ blockSums, int nb) {
    __shared__ int sh[256];
    int t = threadIdx.x;
    int orig = (t < nb) ? blockSums[t] : 0;
    sh[t] = orig;
    __syncthreads();
    for (int off = 1; off < 256; off <<= 1) {
        int v = (t >= off) ? sh[t - off] : 0;
        __syncthreads();
        sh[t] += v;
        __syncthreads();
    }
    if (t < nb) blockSums[t] = sh[t] - orig;
}

__global__ void gscan3_kernel(const int* __restrict__ in, const int* __restrict__ blockBase,
                              int* __restrict__ out, int n) {
    __shared__ int sh[SCAN_C];
    int base = blockIdx.x * SCAN_C;
    int t = threadIdx.x;
    int v0 = (base + t < n) ? in[base + t] : 0;
    int v1 = (base + t + 256 < n) ? in[base + t + 256] : 0;
    sh[t] = v0;
    sh[t + 256] = v1;
    __syncthreads();
    for (int off = 1; off < SCAN_C; off <<= 1) {
        int a = (t >= off) ? sh[t - off] : 0;
        int b = (t + 256 >= off) ? sh[t + 256 - off] : 0;
        __syncthreads();
        sh[t] += a;
        sh[t + 256] += b;
        __syncthreads();
    }
    int bb = blockBase[blockIdx.x];
    if (base + t < n) out[base + t] = bb + sh[t] - v0;
    if (base + t + 256 < n) out[base + t + 256] = bb + sh[t + 256] - v1;
}

__global__ void bucket_scatter_kernel(const void* __restrict__ eidx, const int* __restrict__ flag,
                                      const int* __restrict__ bases2D, unsigned int* __restrict__ ebuf,
                                      int E, int NB, int EPC) {
    __shared__ int cur[NBMAX];
    int c = blockIdx.x;
    for (int i = threadIdx.x; i < NB; i += blockDim.x) cur[i] = bases2D[i * CH + c];
    __syncthreads();
    int is64 = flag[0];
    int end = min(E, (c + 1) * EPC);
    for (int e = c * EPC + threadIdx.x; e < end; e += blockDim.x) {
        int s = load_idx(eidx, e, is64);
        int d = load_idx(eidx, (long long)E + e, is64);
        int b = d >> BKT_SHIFT;
        int pos = atomicAdd(&cur[b], 1);
        ebuf[pos] = ((unsigned)s << BKT_SHIFT) | (unsigned)(d & (BKT - 1));
    }
}

__global__ __launch_bounds__(BKT)
void bucket_csr_kernel(const unsigned int* __restrict__ ebuf, const int* __restrict__ bases2D,
                       int* __restrict__ offsets, int* __restrict__ srcs, int E, int N, int NB) {
    __shared__ int lcnt[BKT];
    __shared__ int sh[BKT];
    __shared__ int lcur[BKT];
    int b = blockIdx.x;
    int t = threadIdx.x;
    int start = bases2D[b * CH];
    int end = (b + 1 < NB) ? bases2D[(b + 1) * CH] : E;
    lcnt[t] = 0;
    __syncthreads();
    for (int e = start + t; e < end; e += BKT)
        atomicAdd(&lcnt[ebuf[e] & (BKT - 1)], 1);
    __syncthreads();
    sh[t] = lcnt[t];
    __syncthreads();
    for (int off = 1; off < BKT; off <<= 1) {
        int v = (t >= off) ? sh[t - off] : 0;
        __syncthreads();
        sh[t] += v;
        __syncthreads();
    }
    int excl = sh[t] - lcnt[t];
    int node = b * BKT + t;
    if (node < N) offsets[node] = start + excl;
    lcur[t] = start + excl;
    __syncthreads();
    for (int e = start + t; e < end; e += BKT) {
        unsigned int p = ebuf[e];
        int pos = atomicAdd(&lcur[p & (BKT - 1)], 1);
        srcs[pos] = (int)(p >> BKT_SHIFT);
    }
    if (b == 0 && t == 0) offsets[N] = E;
}

// ---------------- fused mean-aggregation + dual MFMA GEMM ----------------
// Block = 512 thr (8 waves), 128 output rows, grid = ceil(N/128).
// Phase A: 32 groups of 16 lanes gather-mean 4 rows each. srcs batched 16 at a
//   time via one coalesced lane-load + __shfl broadcast -> up to 16 independent
//   row-gathers in flight (breaks the srcs->gather dependent-latency chain of
//   the old agg_kernel). Mean rows land in Mt LDS (bf16, 16B chunks XOR-swizzled
//   by row so Phase-B A-fragment ds_read_b128 avoids the stride-256B bank wall).
// Phase B: per K-step, one 8 KB W ks-slice is staged cooperatively into LDS
//   (512 thr x 16 B = exactly one slice), consumed by all 8 waves. Keeps W
//   traffic at ~64 KB/block (~50 MB/layer, L2-hot) without the 64 KB LDS copy
//   that would cap occupancy at 1 block/CU and starve the gather phase.
// LDS: Mt 34.8K + Ws 8K + smin 4K = 47K -> 2 blocks/CU at <=128 VGPR.
__global__ __launch_bounds__(512, 4)
void fused_sage_kernel(const unsigned short* __restrict__ xmain,
                       const unsigned short* __restrict__ xalt,
                       const int* __restrict__ flag,
                       const int* __restrict__ offsets,
                       const int* __restrict__ srcs,
                       const unsigned short* __restrict__ Wpack,
                       const float* __restrict__ bl,
                       unsigned short* __restrict__ outb,
                       unsigned int* __restrict__ minbuf,
                       int N, int relu, int do_min) {
    __shared__ unsigned short Mt[128][136];   // mean tile; reused as Otile in epilogue
    __shared__ unsigned short Ws[8 * 64 * 8]; // one W ks-slice (8 KB)
    __shared__ float smin[8][D];

    const unsigned short* xb = flag[1] ? xalt : xmain;
    const uint4* xp = (const uint4*)xb;
    const int tid = threadIdx.x;
    const int wave = tid >> 6;
    const int lane = tid & 63;
    const int node0 = blockIdx.x * 128;

    // ---- Phase A: gather + mean into Mt ----
    {
        const int g  = tid >> 4;            // 0..31
        const int gl = tid & 15;            // lane in group
        const int gw = g & 3;               // group within wave
        const int r0 = wave * 16 + gw * 4;  // wave-local rows
        for (int i = 0; i < 4; ++i) {
            const int row = r0 + i;
            const int node = node0 + row;
            float acc[8];
#pragma unroll
            for (int q = 0; q < 8; ++q) acc[q] = 0.f;
            int beg = 0, end = 0;
            if (node < N) { beg = offsets[node]; end = offsets[node + 1]; }
            for (int j = beg; j < end; j += 16) {
                const int nrem = end - j;
                int myS = 0;
                if (gl < nrem) myS = __builtin_nontemporal_load(&srcs[j + gl]);
                if (nrem >= 16) {
#pragma unroll
                    for (int e = 0; e < 16; ++e) {
                        int s = __shfl(myS, (gw << 4) + e, 64);
                        uint4 v = xp[(size_t)s * 16 + gl];
                        acc[0] += bf16_to_f(v.x & 0xFFFFu); acc[1] += bf16_to_f(v.x >> 16);
                        acc[2] += bf16_to_f(v.y & 0xFFFFu); acc[3] += bf16_to_f(v.y >> 16);
                        acc[4] += bf16_to_f(v.z & 0xFFFFu); acc[5] += bf16_to_f(v.z >> 16);
                        acc[6] += bf16_to_f(v.w & 0xFFFFu); acc[7] += bf16_to_f(v.w >> 16);
                    }
                } else {
                    for (int e = 0; e < nrem; ++e) {
                        int s = __shfl(myS, (gw << 4) + e, 64);
                        uint4 v = xp[(size_t)s * 16 + gl];
                        acc[0] += bf16_to_f(v.x & 0xFFFFu); acc[1] += bf16_to_f(v.x >> 16);
                        acc[2] += bf16_to_f(v.y & 0xFFFFu); acc[3] += bf16_to_f(v.y >> 16);
                        acc[4] += bf16_to_f(v.z & 0xFFFFu); acc[5] += bf16_to_f(v.z >> 16);
                        acc[6] += bf16_to_f(v.w & 0xFFFFu); acc[7] += bf16_to_f(v.w >> 16);
                    }
                }
            }
            float inv = (end > beg) ? 1.0f / (float)(end - beg) : 0.f;
            uint4 o;
            o.x = (unsigned)f_to_bf16(acc[0] * inv) | ((unsigned)f_to_bf16(acc[1] * inv) << 16);
            o.y = (unsigned)f_to_bf16(acc[2] * inv) | ((unsigned)f_to_bf16(acc[3] * inv) << 16);
            o.z = (unsigned)f_to_bf16(acc[4] * inv) | ((unsigned)f_to_bf16(acc[5] * inv) << 16);
            o.w = (unsigned)f_to_bf16(acc[6] * inv) | ((unsigned)f_to_bf16(acc[7] * inv) << 16);
            // chunk-XOR swizzle: logical 16B chunk gl stored at gl ^ (row&15)
            *(uint4*)&Mt[row][(gl ^ (row & 15)) << 3] = o;
        }
    }
    __syncthreads();

    // ---- Phase B: dual GEMM ----
    const int m16 = lane & 15;
    const int quad = lane >> 4;
    const int arow = node0 + wave * 16 + m16;
    const bool rvalid = arow < N;
    const uint4* wsrc = (const uint4*)Wpack;
    uint4* Wsv = (uint4*)Ws;

    f32x4 acc2[8];
#pragma unroll
    for (int i = 0; i < 8; ++i) acc2[i] = (f32x4)0.0f;

    for (int ks = 0; ks < 8; ++ks) {
        // cooperative stage of this ks-slice: wave w loads nt=w fragment row
        uint4 wv = wsrc[(wave * 8 + ks) * 64 + lane];
        bf16x8 afrag;
        if (ks < 4) {
            afrag = *(bf16x8*)&Mt[wave * 16 + m16][((((ks << 2) + quad)) ^ m16) << 3];
        } else {
            uint4 tmp = make_uint4(0u, 0u, 0u, 0u);
            if (rvalid) tmp = *(const uint4*)(xb + (size_t)arow * D + (ks - 4) * 32 + quad * 8);
            afrag = *(bf16x8*)&tmp;
        }
        Wsv[tid] = wv;
        __syncthreads();
#pragma unroll
        for (int nt = 0; nt < 8; ++nt) {
            bf16x8 bfrag = *(const bf16x8*)&Ws[(nt * 64 + lane) << 3];
            acc2[nt] = __builtin_amdgcn_mfma_f32_16x16x32_bf16(afrag, bfrag, acc2[nt], 0, 0, 0);
        }
        __syncthreads();
    }

    if (do_min) {
#pragma unroll
        for (int nt = 0; nt < 8; ++nt) {
            int n = nt * 16 + m16;
            float b = bl[n];
            float m = 3.402823466e38f;
#pragma unroll
            for (int r = 0; r < 4; ++r) {
                int node = node0 + wave * 16 + quad * 4 + r;
                float v = (node < N) ? (acc2[nt][r] + b) : 3.402823466e38f;
                m = fminf(m, v);
            }
            m = fminf(m, __shfl_xor(m, 16, 64));
            m = fminf(m, __shfl_xor(m, 32, 64));
            if (quad == 0) smin[wave][n] = m;
        }
        __syncthreads();
        if (tid < D) {
            float m = smin[0][tid];
#pragma unroll
            for (int w = 1; w < 8; ++w) m = fminf(m, smin[w][tid]);
            unsigned bits = __float_as_uint(m);
            unsigned enc = ((int)bits >= 0) ? (bits ^ 0x80000000u) : ~bits;
            atomicMin(&minbuf[(blockIdx.x & (MREP - 1)) * D + tid], enc);
        }
        return;
    }

    // epilogue: Mt reads all completed (loop-final barrier) -> alias as Otile
    {
        unsigned short (*Ot)[136] = Mt;
#pragma unroll
        for (int nt = 0; nt < 8; ++nt) {
            int n = nt * 16 + m16;
            float b = bl[n];
#pragma unroll
            for (int r = 0; r < 4; ++r) {
                int m = wave * 16 + quad * 4 + r;
                float v = acc2[nt][r] + b;
                if (relu) v = fmaxf(v, 0.f);
                Ot[m][n] = f_to_bf16(v);
            }
        }
        __syncthreads();
        for (int i = tid; i < 128 * 16; i += 512) {
            int row = i >> 4;
            int c = i & 15;
            int n = node0 + row;
            if (n < N) ((uint4*)outb)[(size_t)n * 16 + c] = *(uint4*)&Ot[row][c * 8];
        }
    }
}

// ---------------- decode fused min (parallel replica fold) ----------------
__global__ void min_out_kernel(const unsigned int* __restrict__ minbuf,
                               const int* __restrict__ flag, void* __restrict__ out) {
    __shared__ unsigned int sh[4][D];
    int tid = threadIdx.x;             // 512 threads
    int q = tid >> 7;
    int c = tid & 127;
    unsigned u = 0xFFFFFFFFu;
    for (int r = q; r < MREP; r += 4) u = min(u, minbuf[r * D + c]);
    sh[q][c] = u;
    __syncthreads();
    if (tid < D) {
        unsigned m = min(min(sh[0][tid], sh[1][tid]), min(sh[2][tid], sh[3][tid]));
        unsigned i = (m & 0x80000000u) ? (m ^ 0x80000000u) : ~m;
        union { unsigned i; float f; } cv; cv.i = i;
        if (flag[1]) ((unsigned short*)out)[tid] = f_to_bf16(cv.f);
        else         ((float*)out)[tid] = cv.f;
    }
}

// ---------------- launch ----------------
extern "C" void kernel_launch(void* const* d_in, const int* in_sizes, int n_in,
                              void* d_out, int out_size, void* d_ws, size_t ws_size,
                              hipStream_t stream) {
    const void* x0   = d_in[0];
    const void* eidx = d_in[1];
    const void* Wl0  = d_in[2];
    const void* bl0  = d_in[3];
    const void* Wr0  = d_in[4];

    const int N = in_sizes[0] / D;          // 100000
    const int E = in_sizes[1] / 2;          // 1600000
    const int L = in_sizes[2] / (D * D);    // 3

    char* ws = (char*)d_ws;
    size_t off = 0;
    auto alloc = [&](size_t bytes) -> void* {
        void* p = ws + off;
        off += (bytes + 255) & ~(size_t)255;
        return p;
    };
    unsigned short* xb    = (unsigned short*)alloc((size_t)N * D * 2);
    unsigned short* bufA  = (unsigned short*)alloc((size_t)N * D * 2);
    unsigned short* scratch = (unsigned short*)alloc((size_t)N * D * 2);  // ebuf home
    int*   offsets = (int*)alloc((size_t)(N + 1) * sizeof(int));
    int*   srcs    = (int*)alloc((size_t)E * sizeof(int));
    int*   flag    = (int*)alloc(256);
    unsigned short* Wpack = (unsigned short*)alloc((size_t)L * 8 * 8 * 64 * 8 * 2);
    float* blf     = (float*)alloc((size_t)L * D * sizeof(float));
    unsigned int* minbuf = (unsigned int*)alloc((size_t)MREP * D * sizeof(unsigned int));
    (void)ws_size; (void)n_in; (void)out_size;

    const int NB  = (N + BKT - 1) / BKT;     // 196
    const int EPC = (E + CH - 1) / CH;       // 6250
    const int n2  = NB * CH;                 // 50176
    unsigned int* ebuf = (unsigned int*)scratch;   // not live during GEMM phases
    int* counts2D  = (int*)bufA;
    int* bases2D   = counts2D + n2;
    int* blockSums = bases2D + n2;

    detect_kernel<<<1, 1, 0, stream>>>((const unsigned short*)x0, (const int*)eidx, flag);

    cvt_x_kernel<<<2048, 256, 0, stream>>>(x0, flag, xb, N * D);
    cvt_f_kernel<<<8, 256, 0, stream>>>(bl0, flag, blf, L * D);
    packW_kernel<<<(L * 8 * 8 * 64 + 255) / 256, 256, 0, stream>>>(Wl0, Wr0, flag, Wpack, L);

    hipMemsetAsync(minbuf, 0xFF, (size_t)MREP * D * sizeof(unsigned int), stream);

    bucket_hist_kernel<<<CH, 256, 0, stream>>>(eidx, flag, counts2D, E, NB, EPC);
    const int nb2 = (n2 + SCAN_C - 1) / SCAN_C;
    gscan1_kernel<<<nb2, 256, 0, stream>>>(counts2D, blockSums, n2);
    gscan2_kernel<<<1, 256, 0, stream>>>(blockSums, nb2);
    gscan3_kernel<<<nb2, 256, 0, stream>>>(counts2D, blockSums, bases2D, n2);
    bucket_scatter_kernel<<<CH, 256, 0, stream>>>(eidx, flag, bases2D, ebuf, E, NB, EPC);
    bucket_csr_kernel<<<NB, BKT, 0, stream>>>(ebuf, bases2D, offsets, srcs, E, N, NB);

    const unsigned short* cur     = xb;                        // fp32 path: converted copy
    const unsigned short* cur_alt = (const unsigned short*)x0; // bf16 path: raw input
    unsigned short* nxt = bufA;
    for (int l = 0; l < L; ++l) {
        int last = (l == L - 1);
        fused_sage_kernel<<<(N + 127) / 128, 512, 0, stream>>>(
            cur, cur_alt, flag, offsets, srcs,
            Wpack + (size_t)l * 8 * 8 * 64 * 8, blf + (size_t)l * D,
            nxt, minbuf, N, last ? 0 : 1, last);
        cur = nxt; cur_alt = nxt;
        nxt = (nxt == bufA) ? xb : bufA;
    }

    min_out_kernel<<<1, 512, 0, stream>>>(minbuf, flag, (void*)d_out);
}

// Round 4
// 448.702 us; speedup vs baseline: 1.0976x; 1.0976x over previous
//
#include <hip/hip_runtime.h>
#include <hip/hip_bf16.h>

#define D 128
#define SCAN_C 512
#define BKT 512        // nodes per bucket
#define BKT_SHIFT 9
#define CH 256         // edge chunks
#define NBMAX 512
#define MREP 64        // min-buffer replicas

typedef __attribute__((ext_vector_type(8))) short bf16x8;
typedef __attribute__((ext_vector_type(4))) float f32x4;

// ---------------- bf16 helpers (manual, RN-even) ----------------
__device__ __forceinline__ float bf16_to_f(unsigned int u) {
    union { unsigned int i; float f; } c; c.i = u << 16; return c.f;
}
__device__ __forceinline__ unsigned short f_to_bf16(float f) {
    union { float f; unsigned int i; } c; c.f = f;
    unsigned int r = c.i + 0x7FFFu + ((c.i >> 16) & 1u);
    return (unsigned short)(r >> 16);
}

// ---------------- runtime dtype detection ----------------
__global__ void detect_kernel(const unsigned short* __restrict__ xr,
                              const int* __restrict__ er, int* __restrict__ flag) {
    int plaus = 0;
    for (int i = 0; i < 64; ++i) {
        unsigned short u = xr[2 * i];
        int e = (u >> 7) & 0xFF;
        if (e >= 0x74 && e <= 0x82) plaus++;
    }
    flag[1] = (plaus >= 32) ? 1 : 0;
    int zeros = 0;
    for (int i = 1; i < 128; i += 2) zeros += (er[i] == 0);
    flag[0] = (zeros >= 60) ? 1 : 0;
}

__device__ __forceinline__ int load_idx(const void* p, long long i, int is64) {
    if (is64) return (int)((const long long*)p)[i];
    return ((const int*)p)[i];
}

// ---------------- conversions ----------------
__global__ void cvt_x_kernel(const void* __restrict__ src, const int* __restrict__ flag,
                             unsigned short* __restrict__ dst, int n) {
    if (flag[1]) return;   // bf16 input: no copy needed
    int i = blockIdx.x * blockDim.x + threadIdx.x;
    int stride = gridDim.x * blockDim.x;
    const float* s = (const float*)src;
    for (; i < n; i += stride) dst[i] = f_to_bf16(s[i]);
}

__global__ void cvt_f_kernel(const void* __restrict__ src, const int* __restrict__ flag,
                             float* __restrict__ dst, int n) {
    int is_bf16 = flag[1];
    int i = blockIdx.x * blockDim.x + threadIdx.x;
    int stride = gridDim.x * blockDim.x;
    if (is_bf16) {
        const unsigned short* s = (const unsigned short*)src;
        for (; i < n; i += stride) dst[i] = bf16_to_f(s[i]);
    } else {
        const float* s = (const float*)src;
        for (; i < n; i += stride) dst[i] = s[i];
    }
}

// ---------------- pack W into MFMA B-fragment order ----------------
__global__ void packW_kernel(const void* __restrict__ Wl0, const void* __restrict__ Wr0,
                             const int* __restrict__ flag, unsigned short* __restrict__ Wpack,
                             int L) {
    int idx = blockIdx.x * blockDim.x + threadIdx.x;
    if (idx >= L * 8 * 8 * 64) return;
    int lane = idx & 63;
    int ks = (idx >> 6) & 7;
    int nt = (idx >> 9) & 7;
    int layer = idx >> 12;
    int n = nt * 16 + (lane & 15);
    int k0 = ks * 32 + (lane >> 4) * 8;
    int is_bf16 = flag[1];
    unsigned short outv[8];
#pragma unroll
    for (int j = 0; j < 8; ++j) {
        int k = k0 + j;
        size_t off = (size_t)layer * D * D + (size_t)n * D + (k & 127);
        float v;
        if (is_bf16) {
            const unsigned short* W = (const unsigned short*)((k < D) ? Wl0 : Wr0);
            v = bf16_to_f(W[off]);
        } else {
            const float* W = (const float*)((k < D) ? Wl0 : Wr0);
            v = W[off];
        }
        outv[j] = f_to_bf16(v);
    }
    *(uint4*)&Wpack[(size_t)idx * 8] = *(uint4*)outv;
}

// ---------------- bucketed CSR build ----------------
__global__ void bucket_hist_kernel(const void* __restrict__ eidx, const int* __restrict__ flag,
                                   int* __restrict__ counts2D, int E, int NB, int EPC) {
    __shared__ int hist[NBMAX];
    int c = blockIdx.x;
    for (int i = threadIdx.x; i < NB; i += blockDim.x) hist[i] = 0;
    __syncthreads();
    int is64 = flag[0];
    int end = min(E, (c + 1) * EPC);
    for (int e = c * EPC + threadIdx.x; e < end; e += blockDim.x) {
        int d = load_idx(eidx, (long long)E + e, is64);
        atomicAdd(&hist[d >> BKT_SHIFT], 1);
    }
    __syncthreads();
    for (int i = threadIdx.x; i < NB; i += blockDim.x)
        counts2D[i * CH + c] = hist[i];
}

__global__ void gscan1_kernel(const int* __restrict__ in, int* __restrict__ blockSums, int n) {
    __shared__ int red[256];
    int base = blockIdx.x * SCAN_C;
    int t = threadIdx.x;
    int s = 0;
    if (base + t < n) s += in[base + t];
    if (base + t + 256 < n) s += in[base + t + 256];
    red[t] = s;
    __syncthreads();
    for (int off = 128; off > 0; off >>= 1) {
        if (t < off) red[t] += red[t + off];
        __syncthreads();
    }
    if (t == 0) blockSums[blockIdx.x] = red[0];
}

__global__ void gscan2_kernel(int* __restrict__ blockSums, int nb) {
    __shared__ int sh[256];
    int t = threadIdx.x;
    int orig = (t < nb) ? blockSums[t] : 0;
    sh[t] = orig;
    __syncthreads();
    for (int off = 1; off < 256; off <<= 1) {
        int v = (t >= off) ? sh[t - off] : 0;
        __syncthreads();
        sh[t] += v;
        __syncthreads();
    }
    if (t < nb) blockSums[t] = sh[t] - orig;
}

__global__ void gscan3_kernel(const int* __restrict__ in, const int* __restrict__ blockBase,
                              int* __restrict__ out, int n) {
    __shared__ int sh[SCAN_C];
    int base = blockIdx.x * SCAN_C;
    int t = threadIdx.x;
    int v0 = (base + t < n) ? in[base + t] : 0;
    int v1 = (base + t + 256 < n) ? in[base + t + 256] : 0;
    sh[t] = v0;
    sh[t + 256] = v1;
    __syncthreads();
    for (int off = 1; off < SCAN_C; off <<= 1) {
        int a = (t >= off) ? sh[t - off] : 0;
        int b = (t + 256 >= off) ? sh[t + 256 - off] : 0;
        __syncthreads();
        sh[t] += a;
        sh[t + 256] += b;
        __syncthreads();
    }
    int bb = blockBase[blockIdx.x];
    if (base + t < n) out[base + t] = bb + sh[t] - v0;
    if (base + t + 256 < n) out[base + t + 256] = bb + sh[t + 256] - v1;
}

__global__ void bucket_scatter_kernel(const void* __restrict__ eidx, const int* __restrict__ flag,
                                      const int* __restrict__ bases2D, unsigned int* __restrict__ ebuf,
                                      int E, int NB, int EPC) {
    __shared__ int cur[NBMAX];
    int c = blockIdx.x;
    for (int i = threadIdx.x; i < NB; i += blockDim.x) cur[i] = bases2D[i * CH + c];
    __syncthreads();
    int is64 = flag[0];
    int end = min(E, (c + 1) * EPC);
    for (int e = c * EPC + threadIdx.x; e < end; e += blockDim.x) {
        int s = load_idx(eidx, e, is64);
        int d = load_idx(eidx, (long long)E + e, is64);
        int b = d >> BKT_SHIFT;
        int pos = atomicAdd(&cur[b], 1);
        ebuf[pos] = ((unsigned)s << BKT_SHIFT) | (unsigned)(d & (BKT - 1));
    }
}

__global__ __launch_bounds__(BKT)
void bucket_csr_kernel(const unsigned int* __restrict__ ebuf, const int* __restrict__ bases2D,
                       int* __restrict__ offsets, int* __restrict__ srcs, int E, int N, int NB) {
    __shared__ int lcnt[BKT];
    __shared__ int sh[BKT];
    __shared__ int lcur[BKT];
    int b = blockIdx.x;
    int t = threadIdx.x;
    int start = bases2D[b * CH];
    int end = (b + 1 < NB) ? bases2D[(b + 1) * CH] : E;
    lcnt[t] = 0;
    __syncthreads();
    for (int e = start + t; e < end; e += BKT)
        atomicAdd(&lcnt[ebuf[e] & (BKT - 1)], 1);
    __syncthreads();
    sh[t] = lcnt[t];
    __syncthreads();
    for (int off = 1; off < BKT; off <<= 1) {
        int v = (t >= off) ? sh[t - off] : 0;
        __syncthreads();
        sh[t] += v;
        __syncthreads();
    }
    int excl = sh[t] - lcnt[t];
    int node = b * BKT + t;
    if (node < N) offsets[node] = start + excl;
    lcur[t] = start + excl;
    __syncthreads();
    for (int e = start + t; e < end; e += BKT) {
        unsigned int p = ebuf[e];
        int pos = atomicAdd(&lcur[p & (BKT - 1)], 1);
        srcs[pos] = (int)(p >> BKT_SHIFT);
    }
    if (b == 0 && t == 0) offsets[N] = E;
}

// ---------------- mean aggregation: 1 node per 16-lane group ----------------
// ILP fix vs the 383us baseline: srcs are loaded 16-at-a-time with ONE coalesced
// lane-load, broadcast to the group via __shfl, and the 16 row-gathers issue
// back-to-back (independent). Next srcs batch is prefetched before consuming the
// current one. In-flight gathers/wave ~4 -> ~12-16. Zero LDS; occupancy stays high.
__global__ void agg_kernel(const unsigned short* __restrict__ xmain,
                           const unsigned short* __restrict__ xalt,
                           const int* __restrict__ flag, const int* __restrict__ offsets,
                           const int* __restrict__ srcs, unsigned short* __restrict__ meanb, int N) {
    const unsigned short* xb = flag[1] ? xalt : xmain;
    int g = blockIdx.x * blockDim.x + threadIdx.x;
    int node = g >> 4;
    int lane = g & 15;                       // lane in 16-lane group
    if (node >= N) return;
    const int gw = (threadIdx.x >> 4) & 3;   // group within wave
    const int sbase = gw << 4;               // shfl source base lane
    int beg = offsets[node], end = offsets[node + 1];
    float acc[8];
#pragma unroll
    for (int i = 0; i < 8; ++i) acc[i] = 0.f;
    const uint4* xp = (const uint4*)xb;

    int myS = 0;
    if (beg + lane < end) myS = srcs[beg + lane];
    for (int j = beg; j < end; j += 16) {
        const int nrem = end - j;
        // prefetch next batch before consuming current (breaks serial chain)
        int nextS = 0;
        if (j + 16 + lane < end) nextS = srcs[j + 16 + lane];
        if (nrem >= 16) {
#pragma unroll
            for (int e = 0; e < 16; ++e) {
                int s = __shfl(myS, sbase + e, 64);
                uint4 v = xp[(size_t)s * 16 + lane];
                acc[0] += bf16_to_f(v.x & 0xFFFFu); acc[1] += bf16_to_f(v.x >> 16);
                acc[2] += bf16_to_f(v.y & 0xFFFFu); acc[3] += bf16_to_f(v.y >> 16);
                acc[4] += bf16_to_f(v.z & 0xFFFFu); acc[5] += bf16_to_f(v.z >> 16);
                acc[6] += bf16_to_f(v.w & 0xFFFFu); acc[7] += bf16_to_f(v.w >> 16);
            }
        } else {
            for (int e = 0; e < nrem; ++e) {
                int s = __shfl(myS, sbase + e, 64);
                uint4 v = xp[(size_t)s * 16 + lane];
                acc[0] += bf16_to_f(v.x & 0xFFFFu); acc[1] += bf16_to_f(v.x >> 16);
                acc[2] += bf16_to_f(v.y & 0xFFFFu); acc[3] += bf16_to_f(v.y >> 16);
                acc[4] += bf16_to_f(v.z & 0xFFFFu); acc[5] += bf16_to_f(v.z >> 16);
                acc[6] += bf16_to_f(v.w & 0xFFFFu); acc[7] += bf16_to_f(v.w >> 16);
            }
        }
        myS = nextS;
    }

    float inv = (end > beg) ? 1.0f / (float)(end - beg) : 0.0f;
    uint4 o;
    o.x = (unsigned)f_to_bf16(acc[0] * inv) | ((unsigned)f_to_bf16(acc[1] * inv) << 16);
    o.y = (unsigned)f_to_bf16(acc[2] * inv) | ((unsigned)f_to_bf16(acc[3] * inv) << 16);
    o.z = (unsigned)f_to_bf16(acc[4] * inv) | ((unsigned)f_to_bf16(acc[5] * inv) << 16);
    o.w = (unsigned)f_to_bf16(acc[6] * inv) | ((unsigned)f_to_bf16(acc[7] * inv) << 16);
    ((uint4*)meanb)[(size_t)node * 16 + lane] = o;
}

// ---------------- MFMA dual GEMM, W staged in LDS ----------------
// Block 512 thr (8 waves), 128 rows, 782 blocks.
// Wpack (64 KB) staged once per block -> B-fragments via ds_read_b128;
// store epilogue reuses the W LDS region (128x136 Otile) after a barrier.
__global__ __launch_bounds__(512)
void gemm_mfma_kernel(const unsigned short* __restrict__ meanb,
                      const unsigned short* __restrict__ xmain,
                      const unsigned short* __restrict__ xalt,
                      const int* __restrict__ flag,
                      const unsigned short* __restrict__ Wpack, const float* __restrict__ bl,
                      unsigned short* __restrict__ outb, unsigned int* __restrict__ minbuf,
                      int N, int relu, int do_min) {
    __shared__ unsigned short Wlds[8 * 8 * 64 * 8];   // 64 KB; aliased as Otile in epilogue
    __shared__ float smin[8][D];
    const unsigned short* xb = flag[1] ? xalt : xmain;

    const int tid = threadIdx.x;
    const int wave = tid >> 6;            // 0..7
    const int lane = tid & 63;
    const int m16 = lane & 15;
    const int quad = lane >> 4;
    const int node0 = blockIdx.x * 128;
    const int arow = node0 + wave * 16 + m16;
    const bool rvalid = arow < N;

    // stage W: 4096 uint4, 512 threads, 8 iters, coalesced
    {
        const uint4* wsrc = (const uint4*)Wpack;
        uint4* wdst = (uint4*)Wlds;
#pragma unroll
        for (int i = 0; i < 8; ++i) wdst[tid + i * 512] = wsrc[tid + i * 512];
    }
    __syncthreads();

    f32x4 acc[8];
#pragma unroll
    for (int i = 0; i < 8; ++i) acc[i] = (f32x4)0.0f;

#pragma unroll
    for (int ks = 0; ks < 8; ++ks) {
        uint4 tmp = make_uint4(0u, 0u, 0u, 0u);
        if (rvalid) {
            const unsigned short* base = (ks < 4)
                ? meanb + (size_t)arow * D + ks * 32 + quad * 8
                : xb    + (size_t)arow * D + (ks - 4) * 32 + quad * 8;
            tmp = *(const uint4*)base;
        }
        bf16x8 afrag = *(bf16x8*)&tmp;
#pragma unroll
        for (int nt = 0; nt < 8; ++nt) {
            bf16x8 bfrag = *(const bf16x8*)&Wlds[((nt * 8 + ks) * 64 + lane) * 8];
            acc[nt] = __builtin_amdgcn_mfma_f32_16x16x32_bf16(afrag, bfrag, acc[nt], 0, 0, 0);
        }
    }

    if (do_min) {
#pragma unroll
        for (int nt = 0; nt < 8; ++nt) {
            int n = nt * 16 + m16;
            float b = bl[n];
            float m = 3.402823466e38f;
#pragma unroll
            for (int r = 0; r < 4; ++r) {
                int node = node0 + wave * 16 + quad * 4 + r;
                float v = (node < N) ? (acc[nt][r] + b) : 3.402823466e38f;
                m = fminf(m, v);
            }
            m = fminf(m, __shfl_xor(m, 16, 64));
            m = fminf(m, __shfl_xor(m, 32, 64));
            if (quad == 0) smin[wave][n] = m;
        }
        __syncthreads();
        if (tid < D) {
            float m = smin[0][tid];
#pragma unroll
            for (int w = 1; w < 8; ++w) m = fminf(m, smin[w][tid]);
            unsigned bits = __float_as_uint(m);
            unsigned enc = ((int)bits >= 0) ? (bits ^ 0x80000000u) : ~bits;
            atomicMin(&minbuf[(blockIdx.x & (MREP - 1)) * D + tid], enc);
        }
        return;
    }

    __syncthreads();   // all ds_reads of Wlds complete before aliasing as Otile
    {
        unsigned short (*Ot)[136] = (unsigned short (*)[136])Wlds;   // 128x136 = 34.8 KB
#pragma unroll
        for (int nt = 0; nt < 8; ++nt) {
            int n = nt * 16 + m16;
            float b = bl[n];
#pragma unroll
            for (int r = 0; r < 4; ++r) {
                int m = wave * 16 + quad * 4 + r;
                float v = acc[nt][r] + b;
                if (relu) v = fmaxf(v, 0.f);
                Ot[m][n] = f_to_bf16(v);
            }
        }
        __syncthreads();
        for (int i = tid; i < 128 * 16; i += 512) {
            int row = i >> 4;
            int c = i & 15;
            int n = node0 + row;
            if (n < N) ((uint4*)outb)[(size_t)n * 16 + c] = *(uint4*)&Ot[row][c * 8];
        }
    }
}

// ---------------- decode fused min (parallel replica fold) ----------------
__global__ void min_out_kernel(const unsigned int* __restrict__ minbuf,
                               const int* __restrict__ flag, void* __restrict__ out) {
    __shared__ unsigned int sh[4][D];
    int tid = threadIdx.x;             // 512 threads
    int q = tid >> 7;
    int c = tid & 127;
    unsigned u = 0xFFFFFFFFu;
    for (int r = q; r < MREP; r += 4) u = min(u, minbuf[r * D + c]);
    sh[q][c] = u;
    __syncthreads();
    if (tid < D) {
        unsigned m = min(min(sh[0][tid], sh[1][tid]), min(sh[2][tid], sh[3][tid]));
        unsigned i = (m & 0x80000000u) ? (m ^ 0x80000000u) : ~m;
        union { unsigned i; float f; } cv; cv.i = i;
        if (flag[1]) ((unsigned short*)out)[tid] = f_to_bf16(cv.f);
        else         ((float*)out)[tid] = cv.f;
    }
}

// ---------------- launch ----------------
extern "C" void kernel_launch(void* const* d_in, const int* in_sizes, int n_in,
                              void* d_out, int out_size, void* d_ws, size_t ws_size,
                              hipStream_t stream) {
    const void* x0   = d_in[0];
    const void* eidx = d_in[1];
    const void* Wl0  = d_in[2];
    const void* bl0  = d_in[3];
    const void* Wr0  = d_in[4];

    const int N = in_sizes[0] / D;          // 100000
    const int E = in_sizes[1] / 2;          // 1600000
    const int L = in_sizes[2] / (D * D);    // 3

    char* ws = (char*)d_ws;
    size_t off = 0;
    auto alloc = [&](size_t bytes) -> void* {
        void* p = ws + off;
        off += (bytes + 255) & ~(size_t)255;
        return p;
    };
    unsigned short* xb    = (unsigned short*)alloc((size_t)N * D * 2);
    unsigned short* bufA  = (unsigned short*)alloc((size_t)N * D * 2);
    unsigned short* meanb = (unsigned short*)alloc((size_t)N * D * 2);
    int*   offsets = (int*)alloc((size_t)(N + 1) * sizeof(int));
    int*   srcs    = (int*)alloc((size_t)E * sizeof(int));
    int*   flag    = (int*)alloc(256);
    unsigned short* Wpack = (unsigned short*)alloc((size_t)L * 8 * 8 * 64 * 8 * 2);
    float* blf     = (float*)alloc((size_t)L * D * sizeof(float));
    unsigned int* minbuf = (unsigned int*)alloc((size_t)MREP * D * sizeof(unsigned int));
    (void)ws_size; (void)n_in; (void)out_size;

    const int NB  = (N + BKT - 1) / BKT;     // 196
    const int EPC = (E + CH - 1) / CH;       // 6250
    const int n2  = NB * CH;                 // 50176
    unsigned int* ebuf = (unsigned int*)meanb;   // aliased: not live during CSR build
    int* counts2D  = (int*)bufA;
    int* bases2D   = counts2D + n2;
    int* blockSums = bases2D + n2;

    detect_kernel<<<1, 1, 0, stream>>>((const unsigned short*)x0, (const int*)eidx, flag);

    cvt_x_kernel<<<2048, 256, 0, stream>>>(x0, flag, xb, N * D);
    cvt_f_kernel<<<8, 256, 0, stream>>>(bl0, flag, blf, L * D);
    packW_kernel<<<(L * 8 * 8 * 64 + 255) / 256, 256, 0, stream>>>(Wl0, Wr0, flag, Wpack, L);

    hipMemsetAsync(minbuf, 0xFF, (size_t)MREP * D * sizeof(unsigned int), stream);

    bucket_hist_kernel<<<CH, 256, 0, stream>>>(eidx, flag, counts2D, E, NB, EPC);
    const int nb2 = (n2 + SCAN_C - 1) / SCAN_C;
    gscan1_kernel<<<nb2, 256, 0, stream>>>(counts2D, blockSums, n2);
    gscan2_kernel<<<1, 256, 0, stream>>>(blockSums, nb2);
    gscan3_kernel<<<nb2, 256, 0, stream>>>(counts2D, blockSums, bases2D, n2);
    bucket_scatter_kernel<<<CH, 256, 0, stream>>>(eidx, flag, bases2D, ebuf, E, NB, EPC);
    bucket_csr_kernel<<<NB, BKT, 0, stream>>>(ebuf, bases2D, offsets, srcs, E, N, NB);

    const unsigned short* cur     = xb;                        // fp32 path: converted copy
    const unsigned short* cur_alt = (const unsigned short*)x0; // bf16 path: raw input
    unsigned short* nxt = bufA;
    for (int l = 0; l < L; ++l) {
        int last = (l == L - 1);
        int agg_blocks = (N * 16 + 255) / 256;
        agg_kernel<<<agg_blocks, 256, 0, stream>>>(cur, cur_alt, flag, offsets, srcs, meanb, N);
        gemm_mfma_kernel<<<(N + 127) / 128, 512, 0, stream>>>(
            meanb, cur, cur_alt, flag, Wpack + (size_t)l * 8 * 8 * 64 * 8, blf + (size_t)l * D,
            nxt, minbuf, N, last ? 0 : 1, last);
        cur = nxt; cur_alt = nxt;
        nxt = (nxt == bufA) ? xb : bufA;
    }

    min_out_kernel<<<1, 512, 0, stream>>>(minbuf, flag, (void*)d_out);
}

// Round 5
// 385.857 us; speedup vs baseline: 1.2764x; 1.1629x over previous
//
#include <hip/hip_runtime.h>
#include <hip/hip_bf16.h>

#define D 128
#define SCAN_C 512
#define BKT 512        // nodes per bucket
#define BKT_SHIFT 9
#define CH 256         // edge chunks
#define NBMAX 512
#define MREP 64        // min-buffer replicas

typedef __attribute__((ext_vector_type(8))) short bf16x8;
typedef __attribute__((ext_vector_type(4))) float f32x4;

// ---------------- bf16 helpers (manual, RN-even) ----------------
__device__ __forceinline__ float bf16_to_f(unsigned int u) {
    union { unsigned int i; float f; } c; c.i = u << 16; return c.f;
}
__device__ __forceinline__ unsigned short f_to_bf16(float f) {
    union { float f; unsigned int i; } c; c.f = f;
    unsigned int r = c.i + 0x7FFFu + ((c.i >> 16) & 1u);
    return (unsigned short)(r >> 16);
}

// ---------------- runtime dtype detection ----------------
__global__ void detect_kernel(const unsigned short* __restrict__ xr,
                              const int* __restrict__ er, int* __restrict__ flag) {
    int plaus = 0;
    for (int i = 0; i < 64; ++i) {
        unsigned short u = xr[2 * i];
        int e = (u >> 7) & 0xFF;
        if (e >= 0x74 && e <= 0x82) plaus++;
    }
    flag[1] = (plaus >= 32) ? 1 : 0;
    int zeros = 0;
    for (int i = 1; i < 128; i += 2) zeros += (er[i] == 0);
    flag[0] = (zeros >= 60) ? 1 : 0;
}

__device__ __forceinline__ int load_idx(const void* p, long long i, int is64) {
    if (is64) return (int)((const long long*)p)[i];
    return ((const int*)p)[i];
}

// ---------------- conversions ----------------
__global__ void cvt_x_kernel(const void* __restrict__ src, const int* __restrict__ flag,
                             unsigned short* __restrict__ dst, int n) {
    if (flag[1]) return;   // bf16 input: no copy needed
    int i = blockIdx.x * blockDim.x + threadIdx.x;
    int stride = gridDim.x * blockDim.x;
    const float* s = (const float*)src;
    for (; i < n; i += stride) dst[i] = f_to_bf16(s[i]);
}

__global__ void cvt_f_kernel(const void* __restrict__ src, const int* __restrict__ flag,
                             float* __restrict__ dst, int n) {
    int is_bf16 = flag[1];
    int i = blockIdx.x * blockDim.x + threadIdx.x;
    int stride = gridDim.x * blockDim.x;
    if (is_bf16) {
        const unsigned short* s = (const unsigned short*)src;
        for (; i < n; i += stride) dst[i] = bf16_to_f(s[i]);
    } else {
        const float* s = (const float*)src;
        for (; i < n; i += stride) dst[i] = s[i];
    }
}

// ---------------- pack W into MFMA B-fragment order ----------------
__global__ void packW_kernel(const void* __restrict__ Wl0, const void* __restrict__ Wr0,
                             const int* __restrict__ flag, unsigned short* __restrict__ Wpack,
                             int L) {
    int idx = blockIdx.x * blockDim.x + threadIdx.x;
    if (idx >= L * 8 * 8 * 64) return;
    int lane = idx & 63;
    int ks = (idx >> 6) & 7;
    int nt = (idx >> 9) & 7;
    int layer = idx >> 12;
    int n = nt * 16 + (lane & 15);
    int k0 = ks * 32 + (lane >> 4) * 8;
    int is_bf16 = flag[1];
    unsigned short outv[8];
#pragma unroll
    for (int j = 0; j < 8; ++j) {
        int k = k0 + j;
        size_t off = (size_t)layer * D * D + (size_t)n * D + (k & 127);
        float v;
        if (is_bf16) {
            const unsigned short* W = (const unsigned short*)((k < D) ? Wl0 : Wr0);
            v = bf16_to_f(W[off]);
        } else {
            const float* W = (const float*)((k < D) ? Wl0 : Wr0);
            v = W[off];
        }
        outv[j] = f_to_bf16(v);
    }
    *(uint4*)&Wpack[(size_t)idx * 8] = *(uint4*)outv;
}

// ---------------- bucketed CSR build ----------------
__global__ void bucket_hist_kernel(const void* __restrict__ eidx, const int* __restrict__ flag,
                                   int* __restrict__ counts2D, int E, int NB, int EPC) {
    __shared__ int hist[NBMAX];
    int c = blockIdx.x;
    for (int i = threadIdx.x; i < NB; i += blockDim.x) hist[i] = 0;
    __syncthreads();
    int is64 = flag[0];
    int end = min(E, (c + 1) * EPC);
    for (int e = c * EPC + threadIdx.x; e < end; e += blockDim.x) {
        int d = load_idx(eidx, (long long)E + e, is64);
        atomicAdd(&hist[d >> BKT_SHIFT], 1);
    }
    __syncthreads();
    for (int i = threadIdx.x; i < NB; i += blockDim.x)
        counts2D[i * CH + c] = hist[i];
}

__global__ void gscan1_kernel(const int* __restrict__ in, int* __restrict__ blockSums, int n) {
    __shared__ int red[256];
    int base = blockIdx.x * SCAN_C;
    int t = threadIdx.x;
    int s = 0;
    if (base + t < n) s += in[base + t];
    if (base + t + 256 < n) s += in[base + t + 256];
    red[t] = s;
    __syncthreads();
    for (int off = 128; off > 0; off >>= 1) {
        if (t < off) red[t] += red[t + off];
        __syncthreads();
    }
    if (t == 0) blockSums[blockIdx.x] = red[0];
}

__global__ void gscan2_kernel(int* __restrict__ blockSums, int nb) {
    __shared__ int sh[256];
    int t = threadIdx.x;
    int orig = (t < nb) ? blockSums[t] : 0;
    sh[t] = orig;
    __syncthreads();
    for (int off = 1; off < 256; off <<= 1) {
        int v = (t >= off) ? sh[t - off] : 0;
        __syncthreads();
        sh[t] += v;
        __syncthreads();
    }
    if (t < nb) blockSums[t] = sh[t] - orig;
}

__global__ void gscan3_kernel(const int* __restrict__ in, const int* __restrict__ blockBase,
                              int* __restrict__ out, int n) {
    __shared__ int sh[SCAN_C];
    int base = blockIdx.x * SCAN_C;
    int t = threadIdx.x;
    int v0 = (base + t < n) ? in[base + t] : 0;
    int v1 = (base + t + 256 < n) ? in[base + t + 256] : 0;
    sh[t] = v0;
    sh[t + 256] = v1;
    __syncthreads();
    for (int off = 1; off < SCAN_C; off <<= 1) {
        int a = (t >= off) ? sh[t - off] : 0;
        int b = (t + 256 >= off) ? sh[t + 256 - off] : 0;
        __syncthreads();
        sh[t] += a;
        sh[t + 256] += b;
        __syncthreads();
    }
    int bb = blockBase[blockIdx.x];
    if (base + t < n) out[base + t] = bb + sh[t] - v0;
    if (base + t + 256 < n) out[base + t + 256] = bb + sh[t + 256] - v1;
}

__global__ void bucket_scatter_kernel(const void* __restrict__ eidx, const int* __restrict__ flag,
                                      const int* __restrict__ bases2D, unsigned int* __restrict__ ebuf,
                                      int E, int NB, int EPC) {
    __shared__ int cur[NBMAX];
    int c = blockIdx.x;
    for (int i = threadIdx.x; i < NB; i += blockDim.x) cur[i] = bases2D[i * CH + c];
    __syncthreads();
    int is64 = flag[0];
    int end = min(E, (c + 1) * EPC);
    for (int e = c * EPC + threadIdx.x; e < end; e += blockDim.x) {
        int s = load_idx(eidx, e, is64);
        int d = load_idx(eidx, (long long)E + e, is64);
        int b = d >> BKT_SHIFT;
        int pos = atomicAdd(&cur[b], 1);
        ebuf[pos] = ((unsigned)s << BKT_SHIFT) | (unsigned)(d & (BKT - 1));
    }
}

__global__ __launch_bounds__(BKT)
void bucket_csr_kernel(const unsigned int* __restrict__ ebuf, const int* __restrict__ bases2D,
                       int* __restrict__ offsets, int* __restrict__ srcs, int E, int N, int NB) {
    __shared__ int lcnt[BKT];
    __shared__ int sh[BKT];
    __shared__ int lcur[BKT];
    int b = blockIdx.x;
    int t = threadIdx.x;
    int start = bases2D[b * CH];
    int end = (b + 1 < NB) ? bases2D[(b + 1) * CH] : E;
    lcnt[t] = 0;
    __syncthreads();
    for (int e = start + t; e < end; e += BKT)
        atomicAdd(&lcnt[ebuf[e] & (BKT - 1)], 1);
    __syncthreads();
    sh[t] = lcnt[t];
    __syncthreads();
    for (int off = 1; off < BKT; off <<= 1) {
        int v = (t >= off) ? sh[t - off] : 0;
        __syncthreads();
        sh[t] += v;
        __syncthreads();
    }
    int excl = sh[t] - lcnt[t];
    int node = b * BKT + t;
    if (node < N) offsets[node] = start + excl;
    lcur[t] = start + excl;
    __syncthreads();
    for (int e = start + t; e < end; e += BKT) {
        unsigned int p = ebuf[e];
        int pos = atomicAdd(&lcur[p & (BKT - 1)], 1);
        srcs[pos] = (int)(p >> BKT_SHIFT);
    }
    if (b == 0 && t == 0) offsets[N] = E;
}

// ---------------- mean aggregation: 1 node per 16-lane group, 8-deep pipeline ----------------
// Evidence from r3/r4: gather BW scales with resident waves x in-flight gathers.
// Baseline 4-wide achieved only ~2 effective in-flight/wave. This version issues
// 8 independent row-gathers back-to-back from direct (group-uniform, L1-broadcast)
// srcs loads. No shfl (r4: ds_bpermute in the addr chain hurt), no LDS (r3: occupancy
// collapse). Peak live regs ~56 (8 uint4 in flight + 8 acc) -- under the 64-VGPR
// 8-waves/SIMD boundary.
__global__ void agg_kernel(const unsigned short* __restrict__ xmain,
                           const unsigned short* __restrict__ xalt,
                           const int* __restrict__ flag, const int* __restrict__ offsets,
                           const int* __restrict__ srcs, unsigned short* __restrict__ meanb, int N) {
    const unsigned short* xb = flag[1] ? xalt : xmain;
    int g = blockIdx.x * blockDim.x + threadIdx.x;
    int node = g >> 4;
    int lane = g & 15;
    if (node >= N) return;
    int beg = offsets[node], end = offsets[node + 1];
    float acc[8];
#pragma unroll
    for (int i = 0; i < 8; ++i) acc[i] = 0.f;
    const uint4* xp = (const uint4*)xb;

#define ACC8(v)                                                              \
    acc[0] += bf16_to_f((v).x & 0xFFFFu); acc[1] += bf16_to_f((v).x >> 16);  \
    acc[2] += bf16_to_f((v).y & 0xFFFFu); acc[3] += bf16_to_f((v).y >> 16);  \
    acc[4] += bf16_to_f((v).z & 0xFFFFu); acc[5] += bf16_to_f((v).z >> 16);  \
    acc[6] += bf16_to_f((v).w & 0xFFFFu); acc[7] += bf16_to_f((v).w >> 16);

    int j = beg;
    for (; j + 7 < end; j += 8) {
        int s0 = srcs[j];     int s1 = srcs[j + 1];
        int s2 = srcs[j + 2]; int s3 = srcs[j + 3];
        int s4 = srcs[j + 4]; int s5 = srcs[j + 5];
        int s6 = srcs[j + 6]; int s7 = srcs[j + 7];
        uint4 v0 = xp[(size_t)s0 * 16 + lane];
        uint4 v1 = xp[(size_t)s1 * 16 + lane];
        uint4 v2 = xp[(size_t)s2 * 16 + lane];
        uint4 v3 = xp[(size_t)s3 * 16 + lane];
        uint4 v4 = xp[(size_t)s4 * 16 + lane];
        uint4 v5 = xp[(size_t)s5 * 16 + lane];
        uint4 v6 = xp[(size_t)s6 * 16 + lane];
        uint4 v7 = xp[(size_t)s7 * 16 + lane];
        ACC8(v0); ACC8(v1); ACC8(v2); ACC8(v3);
        ACC8(v4); ACC8(v5); ACC8(v6); ACC8(v7);
    }
    if (j + 3 < end) {
        int s0 = srcs[j];     int s1 = srcs[j + 1];
        int s2 = srcs[j + 2]; int s3 = srcs[j + 3];
        uint4 v0 = xp[(size_t)s0 * 16 + lane];
        uint4 v1 = xp[(size_t)s1 * 16 + lane];
        uint4 v2 = xp[(size_t)s2 * 16 + lane];
        uint4 v3 = xp[(size_t)s3 * 16 + lane];
        ACC8(v0); ACC8(v1); ACC8(v2); ACC8(v3);
        j += 4;
    }
    for (; j < end; ++j) {
        uint4 v = xp[(size_t)srcs[j] * 16 + lane];
        ACC8(v);
    }
#undef ACC8

    float inv = (end > beg) ? 1.0f / (float)(end - beg) : 0.0f;
    uint4 o;
    o.x = (unsigned)f_to_bf16(acc[0] * inv) | ((unsigned)f_to_bf16(acc[1] * inv) << 16);
    o.y = (unsigned)f_to_bf16(acc[2] * inv) | ((unsigned)f_to_bf16(acc[3] * inv) << 16);
    o.z = (unsigned)f_to_bf16(acc[4] * inv) | ((unsigned)f_to_bf16(acc[5] * inv) << 16);
    o.w = (unsigned)f_to_bf16(acc[6] * inv) | ((unsigned)f_to_bf16(acc[7] * inv) << 16);
    ((uint4*)meanb)[(size_t)node * 16 + lane] = o;
}

// ---------------- MFMA dual GEMM, W staged in LDS ----------------
__global__ __launch_bounds__(512)
void gemm_mfma_kernel(const unsigned short* __restrict__ meanb,
                      const unsigned short* __restrict__ xmain,
                      const unsigned short* __restrict__ xalt,
                      const int* __restrict__ flag,
                      const unsigned short* __restrict__ Wpack, const float* __restrict__ bl,
                      unsigned short* __restrict__ outb, unsigned int* __restrict__ minbuf,
                      int N, int relu, int do_min) {
    __shared__ unsigned short Wlds[8 * 8 * 64 * 8];   // 64 KB; aliased as Otile in epilogue
    __shared__ float smin[8][D];
    const unsigned short* xb = flag[1] ? xalt : xmain;

    const int tid = threadIdx.x;
    const int wave = tid >> 6;            // 0..7
    const int lane = tid & 63;
    const int m16 = lane & 15;
    const int quad = lane >> 4;
    const int node0 = blockIdx.x * 128;
    const int arow = node0 + wave * 16 + m16;
    const bool rvalid = arow < N;

    // stage W: 4096 uint4, 512 threads, 8 iters, coalesced
    {
        const uint4* wsrc = (const uint4*)Wpack;
        uint4* wdst = (uint4*)Wlds;
#pragma unroll
        for (int i = 0; i < 8; ++i) wdst[tid + i * 512] = wsrc[tid + i * 512];
    }
    __syncthreads();

    f32x4 acc[8];
#pragma unroll
    for (int i = 0; i < 8; ++i) acc[i] = (f32x4)0.0f;

#pragma unroll
    for (int ks = 0; ks < 8; ++ks) {
        uint4 tmp = make_uint4(0u, 0u, 0u, 0u);
        if (rvalid) {
            const unsigned short* base = (ks < 4)
                ? meanb + (size_t)arow * D + ks * 32 + quad * 8
                : xb    + (size_t)arow * D + (ks - 4) * 32 + quad * 8;
            tmp = *(const uint4*)base;
        }
        bf16x8 afrag = *(bf16x8*)&tmp;
#pragma unroll
        for (int nt = 0; nt < 8; ++nt) {
            bf16x8 bfrag = *(const bf16x8*)&Wlds[((nt * 8 + ks) * 64 + lane) * 8];
            acc[nt] = __builtin_amdgcn_mfma_f32_16x16x32_bf16(afrag, bfrag, acc[nt], 0, 0, 0);
        }
    }

    if (do_min) {
#pragma unroll
        for (int nt = 0; nt < 8; ++nt) {
            int n = nt * 16 + m16;
            float b = bl[n];
            float m = 3.402823466e38f;
#pragma unroll
            for (int r = 0; r < 4; ++r) {
                int node = node0 + wave * 16 + quad * 4 + r;
                float v = (node < N) ? (acc[nt][r] + b) : 3.402823466e38f;
                m = fminf(m, v);
            }
            m = fminf(m, __shfl_xor(m, 16, 64));
            m = fminf(m, __shfl_xor(m, 32, 64));
            if (quad == 0) smin[wave][n] = m;
        }
        __syncthreads();
        if (tid < D) {
            float m = smin[0][tid];
#pragma unroll
            for (int w = 1; w < 8; ++w) m = fminf(m, smin[w][tid]);
            unsigned bits = __float_as_uint(m);
            unsigned enc = ((int)bits >= 0) ? (bits ^ 0x80000000u) : ~bits;
            atomicMin(&minbuf[(blockIdx.x & (MREP - 1)) * D + tid], enc);
        }
        return;
    }

    __syncthreads();   // all ds_reads of Wlds complete before aliasing as Otile
    {
        unsigned short (*Ot)[136] = (unsigned short (*)[136])Wlds;   // 128x136 = 34.8 KB
#pragma unroll
        for (int nt = 0; nt < 8; ++nt) {
            int n = nt * 16 + m16;
            float b = bl[n];
#pragma unroll
            for (int r = 0; r < 4; ++r) {
                int m = wave * 16 + quad * 4 + r;
                float v = acc[nt][r] + b;
                if (relu) v = fmaxf(v, 0.f);
                Ot[m][n] = f_to_bf16(v);
            }
        }
        __syncthreads();
        for (int i = tid; i < 128 * 16; i += 512) {
            int row = i >> 4;
            int c = i & 15;
            int n = node0 + row;
            if (n < N) ((uint4*)outb)[(size_t)n * 16 + c] = *(uint4*)&Ot[row][c * 8];
        }
    }
}

// ---------------- decode fused min (parallel replica fold) ----------------
__global__ void min_out_kernel(const unsigned int* __restrict__ minbuf,
                               const int* __restrict__ flag, void* __restrict__ out) {
    __shared__ unsigned int sh[4][D];
    int tid = threadIdx.x;             // 512 threads
    int q = tid >> 7;
    int c = tid & 127;
    unsigned u = 0xFFFFFFFFu;
    for (int r = q; r < MREP; r += 4) u = min(u, minbuf[r * D + c]);
    sh[q][c] = u;
    __syncthreads();
    if (tid < D) {
        unsigned m = min(min(sh[0][tid], sh[1][tid]), min(sh[2][tid], sh[3][tid]));
        unsigned i = (m & 0x80000000u) ? (m ^ 0x80000000u) : ~m;
        union { unsigned i; float f; } cv; cv.i = i;
        if (flag[1]) ((unsigned short*)out)[tid] = f_to_bf16(cv.f);
        else         ((float*)out)[tid] = cv.f;
    }
}

// ---------------- launch ----------------
extern "C" void kernel_launch(void* const* d_in, const int* in_sizes, int n_in,
                              void* d_out, int out_size, void* d_ws, size_t ws_size,
                              hipStream_t stream) {
    const void* x0   = d_in[0];
    const void* eidx = d_in[1];
    const void* Wl0  = d_in[2];
    const void* bl0  = d_in[3];
    const void* Wr0  = d_in[4];

    const int N = in_sizes[0] / D;          // 100000
    const int E = in_sizes[1] / 2;          // 1600000
    const int L = in_sizes[2] / (D * D);    // 3

    char* ws = (char*)d_ws;
    size_t off = 0;
    auto alloc = [&](size_t bytes) -> void* {
        void* p = ws + off;
        off += (bytes + 255) & ~(size_t)255;
        return p;
    };
    unsigned short* xb    = (unsigned short*)alloc((size_t)N * D * 2);
    unsigned short* bufA  = (unsigned short*)alloc((size_t)N * D * 2);
    unsigned short* meanb = (unsigned short*)alloc((size_t)N * D * 2);
    int*   offsets = (int*)alloc((size_t)(N + 1) * sizeof(int));
    int*   srcs    = (int*)alloc((size_t)E * sizeof(int));
    int*   flag    = (int*)alloc(256);
    unsigned short* Wpack = (unsigned short*)alloc((size_t)L * 8 * 8 * 64 * 8 * 2);
    float* blf     = (float*)alloc((size_t)L * D * sizeof(float));
    unsigned int* minbuf = (unsigned int*)alloc((size_t)MREP * D * sizeof(unsigned int));
    (void)ws_size; (void)n_in; (void)out_size;

    const int NB  = (N + BKT - 1) / BKT;     // 196
    const int EPC = (E + CH - 1) / CH;       // 6250
    const int n2  = NB * CH;                 // 50176
    unsigned int* ebuf = (unsigned int*)meanb;   // aliased: not live during CSR build
    int* counts2D  = (int*)bufA;
    int* bases2D   = counts2D + n2;
    int* blockSums = bases2D + n2;

    detect_kernel<<<1, 1, 0, stream>>>((const unsigned short*)x0, (const int*)eidx, flag);

    cvt_x_kernel<<<2048, 256, 0, stream>>>(x0, flag, xb, N * D);
    cvt_f_kernel<<<8, 256, 0, stream>>>(bl0, flag, blf, L * D);
    packW_kernel<<<(L * 8 * 8 * 64 + 255) / 256, 256, 0, stream>>>(Wl0, Wr0, flag, Wpack, L);

    hipMemsetAsync(minbuf, 0xFF, (size_t)MREP * D * sizeof(unsigned int), stream);

    bucket_hist_kernel<<<CH, 256, 0, stream>>>(eidx, flag, counts2D, E, NB, EPC);
    const int nb2 = (n2 + SCAN_C - 1) / SCAN_C;
    gscan1_kernel<<<nb2, 256, 0, stream>>>(counts2D, blockSums, n2);
    gscan2_kernel<<<1, 256, 0, stream>>>(blockSums, nb2);
    gscan3_kernel<<<nb2, 256, 0, stream>>>(counts2D, blockSums, bases2D, n2);
    bucket_scatter_kernel<<<CH, 256, 0, stream>>>(eidx, flag, bases2D, ebuf, E, NB, EPC);
    bucket_csr_kernel<<<NB, BKT, 0, stream>>>(ebuf, bases2D, offsets, srcs, E, N, NB);

    const unsigned short* cur     = xb;                        // fp32 path: converted copy
    const unsigned short* cur_alt = (const unsigned short*)x0; // bf16 path: raw input
    unsigned short* nxt = bufA;
    for (int l = 0; l < L; ++l) {
        int last = (l == L - 1);
        int agg_blocks = (N * 16 + 255) / 256;
        agg_kernel<<<agg_blocks, 256, 0, stream>>>(cur, cur_alt, flag, offsets, srcs, meanb, N);
        gemm_mfma_kernel<<<(N + 127) / 128, 512, 0, stream>>>(
            meanb, cur, cur_alt, flag, Wpack + (size_t)l * 8 * 8 * 64 * 8, blf + (size_t)l * D,
            nxt, minbuf, N, last ? 0 : 1, last);
        cur = nxt; cur_alt = nxt;
        nxt = (nxt == bufA) ? xb : bufA;
    }

    min_out_kernel<<<1, 512, 0, stream>>>(minbuf, flag, (void*)d_out);
}